// Round 2
// baseline (1260.483 us; speedup 1.0000x reference)
//
#include <hip/hip_runtime.h>
#include <math.h>

#define H 4096
#define E 64
#define BR 64          // rows per block (= wave size; each lane owns one row)
#define BK 64          // k-window
#define NT 512         // threads = 8 waves
#define NW 8           // waves per block
#define EW 8           // experts per wave
#define XSTR 68        // LDS row stride in floats (17 float4s, odd -> conflict-free)

// ---- kernel 1: transpose w [64][4096] -> wt [4096][64] (1 MB in d_ws) ----
__global__ __launch_bounds__(256) void transpose_w(const float* __restrict__ w,
                                                   float* __restrict__ wt) {
    __shared__ float tile[64][68];
    const int t = threadIdx.x;
    const int k0 = blockIdx.x * 64;
#pragma unroll
    for (int p = 0; p < 4; ++p) {
        const int f = t + 256 * p;
        const int e = f >> 4, kq = f & 15;
        float4 v = *(const float4*)(w + (size_t)e * H + k0 + (kq << 2));
        tile[e][(kq << 2) + 0] = v.x;
        tile[e][(kq << 2) + 1] = v.y;
        tile[e][(kq << 2) + 2] = v.z;
        tile[e][(kq << 2) + 3] = v.w;
    }
    __syncthreads();
#pragma unroll
    for (int p = 0; p < 4; ++p) {
        const int f = t + 256 * p;
        const int kk = f >> 4, eq = f & 15;
        float4 o;
        o.x = tile[(eq << 2) + 0][kk];
        o.y = tile[(eq << 2) + 1][kk];
        o.z = tile[(eq << 2) + 2][kk];
        o.w = tile[(eq << 2) + 3][kk];
        *(float4*)(wt + (size_t)(k0 + kk) * E + (eq << 2)) = o;
    }
}

// ---- kernel 2: fused GEMM + top-2 + softmax ----
// Wave w handles experts [8w, 8w+8); lane l owns row m0+l fully.
// w values come from SGPRs (uniform loads from wt); LDS carries only x.
__global__ __launch_bounds__(NT) void router_kernel(
    const float* __restrict__ x, const float* __restrict__ wt,
    float* __restrict__ out, int M)
{
    __shared__ __align__(16) float xs[2][BR][XSTR];
    __shared__ __align__(16) float cand[NW][BR][4];

    const int t    = threadIdx.x;
    const int lane = t & 63;
    const int wave = __builtin_amdgcn_readfirstlane(t >> 6);
    const int e0   = wave << 3;               // uniform
    const int m0   = blockIdx.x * BR;

    float* logits   = out;
    float* idx_out  = out + (size_t)M * E;
    float* prob_out = idx_out + (size_t)M * 2;

    // staging: f = t + 512p (p=0,1): row = f>>4 (0..63), c4 = f&15
    const int srow = t >> 4;                  // 0..31
    const int sc4  = t & 15;
    const float* xrow = x + (size_t)(m0 + srow) * H + (sc4 << 2);

    float4 pf[2];
    auto load_tile = [&](int k0) {
#pragma unroll
        for (int p = 0; p < 2; ++p)
            pf[p] = *(const float4*)(xrow + (size_t)(32 * p) * H + k0);
    };
    auto store_tile = [&](int b) {
#pragma unroll
        for (int p = 0; p < 2; ++p)
            *(float4*)&xs[b][srow + 32 * p][sc4 << 2] = pf[p];
    };

    float acc[EW];
#pragma unroll
    for (int j = 0; j < EW; ++j) acc[j] = 0.0f;

    const float* wte = wt + e0;               // uniform base

    load_tile(0);
    store_tile(0);
    __syncthreads();

    const int nwin = H / BK;                  // 64
    for (int win = 0; win < nwin; ++win) {
        const int buf = win & 1;
        if (win + 1 < nwin) load_tile((win + 1) * BK);

#pragma unroll
        for (int k4 = 0; k4 < BK / 4; ++k4) {
            float4 xf = *(const float4*)&xs[buf][lane][k4 << 2];
            const float* wr = wte + (size_t)(win * BK + (k4 << 2)) * E;  // uniform
            const float xa[4] = {xf.x, xf.y, xf.z, xf.w};
#pragma unroll
            for (int kk = 0; kk < 4; ++kk) {
#pragma unroll
                for (int j = 0; j < EW; ++j)
                    acc[j] = fmaf(xa[kk], wr[kk * E + j], acc[j]);
            }
        }

        if (win + 1 < nwin) store_tile(1 - buf);
        __syncthreads();
    }

    // ---- per-lane top-2 over this wave's 8 experts (ascending index) ----
    float v1 = acc[0], v2 = -INFINITY;
    int   i1 = e0,     i2 = -1;
#pragma unroll
    for (int j = 1; j < EW; ++j) {
        const float v = acc[j];
        const int   e = e0 + j;
        if (v > v1)      { v2 = v1; i2 = i1; v1 = v; i1 = e; }
        else if (v > v2) { v2 = v;  i2 = e; }
    }
    cand[wave][lane][0] = v1;
    cand[wave][lane][1] = v2;
    cand[wave][lane][2] = (float)i1;
    cand[wave][lane][3] = (float)i2;

    // ---- logits direct write (two float4 per lane) ----
    const int m = m0 + lane;
    *(float4*)(logits + (size_t)m * E + e0) =
        make_float4(acc[0], acc[1], acc[2], acc[3]);
    *(float4*)(logits + (size_t)m * E + e0 + 4) =
        make_float4(acc[4], acc[5], acc[6], acc[7]);

    __syncthreads();

    // ---- cross-wave merge (wave 0; lane = row), ascending wave order ----
    if (t < BR) {
        float4 c0 = *(const float4*)&cand[0][t][0];
        float V1 = c0.x, V2 = c0.y, I1 = c0.z, I2 = c0.w;
#pragma unroll
        for (int cw = 1; cw < NW; ++cw) {
            float4 c = *(const float4*)&cand[cw][t][0];
            if (c.x > V1) {
                if (c.y > V1) { V2 = c.y; I2 = c.w; }
                else          { V2 = V1;  I2 = I1; }
                V1 = c.x; I1 = c.z;
            } else if (c.x > V2) {
                V2 = c.x; I2 = c.z;
            }
        }
        const int mm = m0 + t;
        const float e2    = __expf(V2 - V1);   // <= 1
        const float denom = 1.0f + e2;
        *(float2*)(idx_out  + (size_t)mm * 2) = make_float2(I1, I2);
        *(float2*)(prob_out + (size_t)mm * 2) = make_float2(1.0f / denom, e2 / denom);
    }
}

extern "C" void kernel_launch(void* const* d_in, const int* in_sizes, int n_in,
                              void* d_out, int out_size, void* d_ws, size_t ws_size,
                              hipStream_t stream) {
    const float* x = (const float*)d_in[0];
    const float* w = (const float*)d_in[1];
    float* wt = (float*)d_ws;                  // 4096*64*4 = 1 MB scratch
    const int M = in_sizes[0] / H;             // 16384 rows

    hipLaunchKernelGGL(transpose_w, dim3(H / 64), dim3(256), 0, stream, w, wt);
    hipLaunchKernelGGL(router_kernel, dim3(M / BR), dim3(NT), 0, stream,
                       x, wt, (float*)d_out, M);
}

// Round 3
// 407.037 us; speedup vs baseline: 3.0967x; 3.0967x over previous
//
#include <hip/hip_runtime.h>
#include <math.h>

#define H 4096
#define E 64
#define BMROWS 32      // rows per block
#define NT 256         // 4 waves; each wave owns a k-quarter
#define KQ 1024        // k per wave
#define BK 32          // k per window (one mfma k-step)
#define NWIN (KQ / BK) // 32 windows

typedef short bf16x8 __attribute__((ext_vector_type(8)));
typedef float f32x4  __attribute__((ext_vector_type(4)));

__device__ __forceinline__ unsigned f2bf_rne_u(float f) {
    unsigned u = __float_as_uint(f);
    return (u + 0x7fffu + ((u >> 16) & 1u)) >> 16;
}

// ---- kernel 1: w fp32 [64][4096] -> w_hi, w_lo bf16 (bits in ushort) ----
__global__ __launch_bounds__(256) void convert_w(const float* __restrict__ w,
                                                 unsigned short* __restrict__ wh,
                                                 unsigned short* __restrict__ wl) {
    const int i = (blockIdx.x * 256 + threadIdx.x) * 4;
    float4 v = *(const float4*)(w + i);
    float vv[4] = {v.x, v.y, v.z, v.w};
    unsigned hh[4], ll[4];
#pragma unroll
    for (int j = 0; j < 4; ++j) {
        hh[j] = f2bf_rne_u(vv[j]);
        float r = vv[j] - __uint_as_float(hh[j] << 16);
        ll[j] = __float_as_uint(r) >> 16;   // truncation: fine for residual
    }
    ushort4 h, l;
    h.x = (unsigned short)hh[0]; h.y = (unsigned short)hh[1];
    h.z = (unsigned short)hh[2]; h.w = (unsigned short)hh[3];
    l.x = (unsigned short)ll[0]; l.y = (unsigned short)ll[1];
    l.z = (unsigned short)ll[2]; l.w = (unsigned short)ll[3];
    *(ushort4*)(wh + i) = h;
    *(ushort4*)(wl + i) = l;
}

// convert 8 consecutive fp32 (two float4) into hi/lo bf16 fragments
__device__ __forceinline__ void cvt8(const float4 a, const float4 b,
                                     bf16x8& hi, bf16x8& lo) {
    float v[8] = {a.x, a.y, a.z, a.w, b.x, b.y, b.z, b.w};
#pragma unroll
    for (int i = 0; i < 8; ++i) {
        unsigned h = f2bf_rne_u(v[i]);
        float r = v[i] - __uint_as_float(h << 16);
        unsigned l = __float_as_uint(r) >> 16;
        hi[i] = (short)h;
        lo[i] = (short)l;
    }
}

// ---- kernel 2: fused hi/lo bf16 MFMA GEMM + top-2 + softmax ----
// Block: 32 rows (2 mfma m-tiles) x 64 experts (4 n-tiles). 4 waves split K.
// No LDS / barriers in main loop; a-frags converted in-register from fp32 x,
// b-frags loaded straight from L2-resident bf16 w planes.
__global__ __launch_bounds__(NT, 2) void router_kernel(
    const float* __restrict__ x,
    const unsigned short* __restrict__ wh,
    const unsigned short* __restrict__ wl,
    float* __restrict__ out, int M)
{
    __shared__ __align__(16) f32x4 merge[8][4][64];   // [acc idx][wave][lane]

    const int t    = threadIdx.x;
    const int lane = t & 63;
    const int wk   = t >> 6;        // k-quarter 0..3
    const int m0   = blockIdx.x * BMROWS;
    const int col  = lane & 15;
    const int quad = lane >> 4;     // 0..3

    const int kbase = wk * KQ + quad * 8;

    const float* xp0 = x + (size_t)(m0 + col) * H + kbase;
    const float* xp1 = x + (size_t)(m0 + 16 + col) * H + kbase;
    const unsigned short* whp = wh + (size_t)col * H + kbase;
    const unsigned short* wlp = wl + (size_t)col * H + kbase;

    f32x4 acc[2][4];
#pragma unroll
    for (int mt = 0; mt < 2; ++mt)
#pragma unroll
        for (int nt = 0; nt < 4; ++nt)
            acc[mt][nt] = (f32x4){0.0f, 0.0f, 0.0f, 0.0f};

    float4 xr[2][2];
    uint4  wrh[4], wrl[4];

    auto loadwin = [&](int win) {
        const int k = win * BK;
        xr[0][0] = *(const float4*)(xp0 + k);
        xr[0][1] = *(const float4*)(xp0 + k + 4);
        xr[1][0] = *(const float4*)(xp1 + k);
        xr[1][1] = *(const float4*)(xp1 + k + 4);
#pragma unroll
        for (int nt = 0; nt < 4; ++nt) {
            wrh[nt] = *(const uint4*)(whp + (size_t)(nt * 16) * H + k);
            wrl[nt] = *(const uint4*)(wlp + (size_t)(nt * 16) * H + k);
        }
    };

    loadwin(0);
#pragma unroll 2
    for (int win = 0; win < NWIN; ++win) {
        // snapshot current window into frags before prefetch overwrites regs
        bf16x8 ah[2], al[2];
        cvt8(xr[0][0], xr[0][1], ah[0], al[0]);
        cvt8(xr[1][0], xr[1][1], ah[1], al[1]);
        bf16x8 bh[4], bl[4];
#pragma unroll
        for (int nt = 0; nt < 4; ++nt) {
            bh[nt] = __builtin_bit_cast(bf16x8, wrh[nt]);
            bl[nt] = __builtin_bit_cast(bf16x8, wrl[nt]);
        }

        if (win + 1 < NWIN) loadwin(win + 1);

#pragma unroll
        for (int nt = 0; nt < 4; ++nt) {
#pragma unroll
            for (int mt = 0; mt < 2; ++mt) {
                acc[mt][nt] = __builtin_amdgcn_mfma_f32_16x16x32_bf16(
                    ah[mt], bh[nt], acc[mt][nt], 0, 0, 0);
                acc[mt][nt] = __builtin_amdgcn_mfma_f32_16x16x32_bf16(
                    ah[mt], bl[nt], acc[mt][nt], 0, 0, 0);
                acc[mt][nt] = __builtin_amdgcn_mfma_f32_16x16x32_bf16(
                    al[mt], bh[nt], acc[mt][nt], 0, 0, 0);
            }
        }
    }

    // ---- cross-wave k-merge via LDS (conflict-free layout) ----
#pragma unroll
    for (int mt = 0; mt < 2; ++mt)
#pragma unroll
        for (int nt = 0; nt < 4; ++nt)
            merge[mt * 4 + nt][wk][lane] = acc[mt][nt];
    __syncthreads();

    if (wk != 0) return;

#pragma unroll
    for (int mt = 0; mt < 2; ++mt)
#pragma unroll
        for (int nt = 0; nt < 4; ++nt) {
#pragma unroll
            for (int w = 1; w < 4; ++w) {
                f32x4 o = merge[mt * 4 + nt][w][lane];
                acc[mt][nt] += o;
            }
        }

    float* logits   = out;
    float* idx_out  = out + (size_t)M * E;
    float* prob_out = idx_out + (size_t)M * 2;

#pragma unroll
    for (int mt = 0; mt < 2; ++mt) {
        const int mrow = m0 + mt * 16 + quad * 4;
#pragma unroll
        for (int r = 0; r < 4; ++r) {
#pragma unroll
            for (int nt = 0; nt < 4; ++nt)
                logits[(size_t)(mrow + r) * E + nt * 16 + col] = acc[mt][nt][r];

            // per-lane top-2 over its 4 experts (ascending index)
            float v1 = acc[mt][0][r], v2 = -INFINITY;
            int   i1 = col,           i2 = 0x7fffffff;
#pragma unroll
            for (int nt = 1; nt < 4; ++nt) {
                const float v = acc[mt][nt][r];
                const int   e = nt * 16 + col;
                if (v > v1)      { v2 = v1; i2 = i1; v1 = v; i1 = e; }
                else if (v > v2) { v2 = v;  i2 = e; }
            }
            // butterfly merge across the 16-lane row group
#pragma unroll
            for (int mask = 1; mask < 16; mask <<= 1) {
                const float ov1 = __shfl_xor(v1, mask);
                const float ov2 = __shfl_xor(v2, mask);
                const int   oi1 = __shfl_xor(i1, mask);
                const int   oi2 = __shfl_xor(i2, mask);
                const bool afirst = (v1 > ov1) || (v1 == ov1 && i1 < oi1);
                float nv1, nv2; int ni1, ni2;
                if (afirst) {
                    nv1 = v1; ni1 = i1;
                    const bool s = (v2 > ov1) || (v2 == ov1 && i2 < oi1);
                    nv2 = s ? v2 : ov1; ni2 = s ? i2 : oi1;
                } else {
                    nv1 = ov1; ni1 = oi1;
                    const bool s = (ov2 > v1) || (ov2 == v1 && oi2 < i1);
                    nv2 = s ? ov2 : v1; ni2 = s ? oi2 : i1;
                }
                v1 = nv1; v2 = nv2; i1 = ni1; i2 = ni2;
            }
            if (col == 0) {
                const int m = mrow + r;
                const float e2 = __expf(v2 - v1);   // <= 1
                const float d  = 1.0f + e2;
                *(float2*)(idx_out  + (size_t)m * 2) = make_float2((float)i1, (float)i2);
                *(float2*)(prob_out + (size_t)m * 2) = make_float2(1.0f / d, e2 / d);
            }
        }
    }
}

extern "C" void kernel_launch(void* const* d_in, const int* in_sizes, int n_in,
                              void* d_out, int out_size, void* d_ws, size_t ws_size,
                              hipStream_t stream) {
    const float* x = (const float*)d_in[0];
    const float* w = (const float*)d_in[1];
    unsigned short* wh = (unsigned short*)d_ws;           // 512 KB
    unsigned short* wl = wh + (size_t)E * H;              // 512 KB
    const int M = in_sizes[0] / H;                        // 16384 rows

    hipLaunchKernelGGL(convert_w, dim3((E * H) / 1024), dim3(256), 0, stream,
                       w, wh, wl);
    hipLaunchKernelGGL(router_kernel, dim3(M / BMROWS), dim3(NT), 0, stream,
                       x, wh, wl, (float*)d_out, M);
}